// Round 4
// baseline (4238.049 us; speedup 1.0000x reference)
//
#include <hip/hip_runtime.h>
#include <hip/hip_bf16.h>

typedef unsigned short u16;
typedef __bf16 bf16x8 __attribute__((ext_vector_type(8)));
typedef float f32x4 __attribute__((ext_vector_type(4)));

#define LOG2PI_F 1.8378770664093453f

__device__ __forceinline__ u16 f2bf(float f) {
  union { __hip_bfloat16 h; u16 u; } cvt;
  cvt.h = __float2bfloat16(f);
  return cvt.u;
}

__device__ __forceinline__ float fast_tanh(float x) {
  float e = __expf(2.0f * x);
  return 1.0f - 2.0f * __builtin_amdgcn_rcpf(e + 1.0f);
}

__device__ __forceinline__ void load_lds16(const void* g, void* l) {
  __builtin_amdgcn_global_load_lds(
      (const __attribute__((address_space(1))) void*)g,
      (__attribute__((address_space(3))) void*)l,
      16, 0, 0);
}

// ---------------- convert obs f32 -> bf16 ----------------
__global__ void cvt_f32_bf16(const float* __restrict__ in, u16* __restrict__ out, int n4) {
  int i = blockIdx.x * blockDim.x + threadIdx.x;
  int stride = gridDim.x * blockDim.x;
  for (int j = i; j < n4; j += stride) {
    float4 v = reinterpret_cast<const float4*>(in)[j];
    ushort4 o;
    o.x = f2bf(v.x); o.y = f2bf(v.y); o.z = f2bf(v.z); o.w = f2bf(v.w);
    reinterpret_cast<ushort4*>(out)[j] = o;
  }
}

// ------- W [H][K][N] f32 -> Wt [H][N][K] bf16, 64x64 LDS-tiled ---------
__global__ void transpose_cvt(const float* __restrict__ W, u16* __restrict__ Wt,
                              int K, int N) {
  __shared__ u16 t[64][66];
  const int a = blockIdx.z;
  const int n0 = blockIdx.x * 64, k0 = blockIdx.y * 64;
  const float* Wh = W + (size_t)a * K * N;
  u16* Wth = Wt + (size_t)a * N * K;
  const int tid = threadIdx.x;
#pragma unroll
  for (int j = 0; j < 16; ++j) {
    int idx = j * 256 + tid;
    int r = idx >> 6, c = idx & 63;
    t[r][c] = f2bf(Wh[(size_t)(k0 + r) * N + n0 + c]);
  }
  __syncthreads();
#pragma unroll
  for (int j = 0; j < 16; ++j) {
    int idx = j * 256 + tid;
    int r = idx >> 6, c = idx & 63;
    Wth[(size_t)(n0 + r) * K + k0 + c] = t[c][r];
  }
}

// -------- batched-head GEMM, 256x256 tile, BK=32, dbuf, 2 blocks/CU -----
// LDS = 2buf x (A+B) x 256x32 bf16 = 64 KiB -> 2 blocks/CU (TLP hides
// barrier/stage stalls across blocks, m114 mechanism).
// A: bf16 [M][K] (per-head stride aHeadStride elems; 0 => shared)
// Bt: bf16 [H][N][K]
// MODE 1: outBf[h][M][N] = bf16(tanh(A@B + bias))
// MODE 2: atomicAdd muAcc[row][h] += sum_col tanh(A@B+bias)*W3[h][col]
template <int MODE>
__global__ __launch_bounds__(512, 4) void gemm256(
    const u16* __restrict__ A, long aHeadStride,
    const u16* __restrict__ Bt,
    const float* __restrict__ bias,
    int M, int N, int K, int gridN,
    u16* __restrict__ outBf,
    const float* __restrict__ W3,
    float* __restrict__ muAcc) {
  __shared__ __align__(16) u16 lds[2][2][256 * 32];   // 64 KiB

  const int tid = threadIdx.x;
  const int w = tid >> 6, l = tid & 63;
  const int wm = w >> 2, wn = w & 3;        // 2x4 waves, each 128x64 of C
  const int lh = l & 15, lg = l >> 4;

  // T1: bijective XCD swizzle (gridDim.x % 8 == 0 by construction)
  const int nwg = gridDim.x;
  const int cpx = nwg >> 3;
  int bid = (blockIdx.x & 7) * cpx + (blockIdx.x >> 3);
  const int bph = (M >> 8) * gridN;          // blocks per head
  const int head = bid / bph;
  const int rem = bid % bph;
  const int m0 = (rem / gridN) << 8;
  const int n0 = (rem % gridN) << 8;

  const u16* Ah = A + (size_t)head * (size_t)aHeadStride;
  const u16* Bh = Bt + (size_t)head * (size_t)N * (size_t)K;

  // T2 both-sides swizzle for 4-slot (64B) rows: slot j ^ ((row>>2)&3).
  // Linear LDS dest (global_load_lds requirement), pre-swizzled global src.
  auto stage = [&](int buf, int kt) {
#pragma unroll
    for (int i = 0; i < 2; ++i) {
      int c = i * 512 + tid;               // 1024 chunks of 16B = 256x32 bf16
      int row = c >> 2, j = c & 3;
      int js = j ^ ((row >> 2) & 3);
      load_lds16(Ah + (size_t)(m0 + row) * K + kt + js * 8, &lds[buf][0][c * 8]);
    }
#pragma unroll
    for (int i = 0; i < 2; ++i) {
      int c = i * 512 + tid;
      int row = c >> 2, j = c & 3;
      int js = j ^ ((row >> 2) & 3);
      load_lds16(Bh + (size_t)(n0 + row) * K + kt + js * 8, &lds[buf][1][c * 8]);
    }
  };

  f32x4 acc[8][4] = {};
  const int NT = K >> 5;

  // prologue: tiles 0,1 in flight (8 loads); drain tile 0 (4 stay in flight)
  stage(0, 0);
  stage(1, 32);
  asm volatile("s_waitcnt vmcnt(4)" ::: "memory");
  __builtin_amdgcn_sched_barrier(0);
  __builtin_amdgcn_s_barrier();

  for (int t = 0; t < NT; ++t) {
    const u16* As = lds[t & 1][0];
    const u16* Bs = lds[t & 1][1];

    bf16x8 bfr[4];
#pragma unroll
    for (int nf = 0; nf < 4; ++nf) {
      int row = wn * 64 + nf * 16 + lh;
      int j = lg ^ ((row >> 2) & 3);
      bfr[nf] = *reinterpret_cast<const bf16x8*>(&Bs[row * 32 + j * 8]);
    }
    bf16x8 af[8];
#pragma unroll
    for (int mf = 0; mf < 8; ++mf) {
      int row = wm * 128 + mf * 16 + lh;
      int j = lg ^ ((row >> 2) & 3);
      af[mf] = *reinterpret_cast<const bf16x8*>(&As[row * 32 + j * 8]);
    }
    __builtin_amdgcn_s_setprio(1);
#pragma unroll
    for (int mf = 0; mf < 8; ++mf)
#pragma unroll
      for (int nf = 0; nf < 4; ++nf)
        acc[mf][nf] = __builtin_amdgcn_mfma_f32_16x16x32_bf16(
            af[mf], bfr[nf], acc[mf][nf], 0, 0, 0);
    __builtin_amdgcn_s_setprio(0);

    // barrier 1: all waves done reading buf[t&1] -> safe to overwrite
    __builtin_amdgcn_s_barrier();
    __builtin_amdgcn_sched_barrier(0);
    if (t + 2 < NT) {
      stage(t & 1, (t + 2) << 5);
      asm volatile("s_waitcnt vmcnt(4)" ::: "memory");  // drain t+1, keep t+2
    } else {
      asm volatile("s_waitcnt vmcnt(0)" ::: "memory");
    }
    __builtin_amdgcn_sched_barrier(0);
    // barrier 2: tile t+1 visible to all waves
    __builtin_amdgcn_s_barrier();
  }

  if (MODE == 1) {
    u16* Oh = outBf + (size_t)head * (size_t)M * (size_t)N;
#pragma unroll
    for (int mf = 0; mf < 8; ++mf) {
#pragma unroll
      for (int ri = 0; ri < 4; ++ri) {
        const int rowg = m0 + wm * 128 + mf * 16 + lg * 4 + ri;
#pragma unroll
        for (int nf = 0; nf < 4; ++nf) {
          const int col = n0 + wn * 64 + nf * 16 + lh;
          float v = acc[mf][nf][ri] + bias[head * N + col];
          Oh[(size_t)rowg * N + col] = f2bf(fast_tanh(v));
        }
      }
    }
  } else {
#pragma unroll
    for (int mf = 0; mf < 8; ++mf) {
#pragma unroll
      for (int ri = 0; ri < 4; ++ri) {
        const int rowg = m0 + wm * 128 + mf * 16 + lg * 4 + ri;
        float p = 0.f;
#pragma unroll
        for (int nf = 0; nf < 4; ++nf) {
          const int col = n0 + wn * 64 + nf * 16 + lh;
          float v = acc[mf][nf][ri] + bias[head * N + col];
          p += fast_tanh(v) * W3[head * N + col];
        }
        p += __shfl_xor(p, 1);
        p += __shfl_xor(p, 2);
        p += __shfl_xor(p, 4);
        p += __shfl_xor(p, 8);
        if (lh == 0) atomicAdd(&muAcc[(size_t)rowg * 32 + head], p);
      }
    }
  }
}

// ------------- finalize: mu = acc + b3; logp reduction -------------
__global__ void finalize_kernel(const float* __restrict__ muAcc,
                                const float* __restrict__ b3,
                                const float* __restrict__ lstd,
                                const float* __restrict__ act,
                                float* __restrict__ out, int M) {
  int b = blockIdx.x * 256 + threadIdx.x;
  if (b >= M) return;
  float lp = 0.f;
#pragma unroll
  for (int a = 0; a < 32; ++a) {
    float mu = muAcc[(size_t)b * 32 + a] + b3[a];
    out[(size_t)b * 32 + a] = mu;
    float ls = lstd[a];
    float z = (act[(size_t)b * 32 + a] - mu) * __expf(-ls);
    lp += -0.5f * (z * z + LOG2PI_F) - ls;
  }
  out[(size_t)M * 32 + b] = lp;
}

extern "C" void kernel_launch(void* const* d_in, const int* in_sizes, int n_in,
                              void* d_out, int out_size, void* d_ws, size_t ws_size,
                              hipStream_t stream) {
  const float* obs = (const float*)d_in[0];
  const float* act = (const float*)d_in[1];
  const float* W1 = (const float*)d_in[2];
  const float* b1 = (const float*)d_in[3];
  const float* W2 = (const float*)d_in[4];
  const float* b2 = (const float*)d_in[5];
  const float* W3 = (const float*)d_in[6];
  const float* b3 = (const float*)d_in[7];
  const float* lstd = (const float*)d_in[8];

  constexpr int B = 4096, OBS = 512, A = 32, H1 = 1024, H2 = 1024;

  u16* obs_bf = (u16*)d_ws;                              // [B][OBS]
  u16* W1t = obs_bf + (size_t)B * OBS;                   // [A][H1][OBS]
  u16* W2t = W1t + (size_t)A * H1 * OBS;                 // [A][H2][H1]
  u16* x1 = W2t + (size_t)A * H2 * H1;                   // [A][B][H1]
  float* muAcc = (float*)(x1 + (size_t)A * B * H1);      // [B][A]
  float* out = (float*)d_out;

  hipMemsetAsync(muAcc, 0, (size_t)B * A * sizeof(float), stream);

  cvt_f32_bf16<<<1024, 256, 0, stream>>>(obs, obs_bf, B * OBS / 4);
  transpose_cvt<<<dim3(H1 / 64, OBS / 64, A), 256, 0, stream>>>(W1, W1t, OBS, H1);
  transpose_cvt<<<dim3(H2 / 64, H1 / 64, A), 256, 0, stream>>>(W2, W2t, H1, H2);

  // 2048 blocks each (divisible by 8 for the XCD swizzle)
  gemm256<1><<<(B / 256) * (H1 / 256) * A, 512, 0, stream>>>(
      obs_bf, 0L, W1t, b1, B, H1, OBS, H1 / 256, x1, nullptr, nullptr);

  gemm256<2><<<(B / 256) * (H2 / 256) * A, 512, 0, stream>>>(
      x1, (long)B * H1, W2t, b2, B, H2, H1, H2 / 256, nullptr, W3, muAcc);

  finalize_kernel<<<B / 256, 256, 0, stream>>>(muAcc, b3, lstd, act, out, B);
}

// Round 5
// 723.552 us; speedup vs baseline: 5.8573x; 5.8573x over previous
//
#include <hip/hip_runtime.h>
#include <hip/hip_bf16.h>

typedef unsigned short u16;
typedef __bf16 bf16x8 __attribute__((ext_vector_type(8)));
typedef float f32x4 __attribute__((ext_vector_type(4)));

#define LOG2PI_F 1.8378770664093453f

__device__ __forceinline__ u16 f2bf(float f) {
  union { __hip_bfloat16 h; u16 u; } cvt;
  cvt.h = __float2bfloat16(f);
  return cvt.u;
}

__device__ __forceinline__ float fast_tanh(float x) {
  float e = __expf(2.0f * x);
  return 1.0f - 2.0f * __builtin_amdgcn_rcpf(e + 1.0f);
}

__device__ __forceinline__ void load_lds16(const void* g, void* l) {
  __builtin_amdgcn_global_load_lds(
      (const __attribute__((address_space(1))) void*)g,
      (__attribute__((address_space(3))) void*)l,
      16, 0, 0);
}

// ---------------- convert obs f32 -> bf16 ----------------
__global__ void cvt_f32_bf16(const float* __restrict__ in, u16* __restrict__ out, int n4) {
  int i = blockIdx.x * blockDim.x + threadIdx.x;
  int stride = gridDim.x * blockDim.x;
  for (int j = i; j < n4; j += stride) {
    float4 v = reinterpret_cast<const float4*>(in)[j];
    ushort4 o;
    o.x = f2bf(v.x); o.y = f2bf(v.y); o.z = f2bf(v.z); o.w = f2bf(v.w);
    reinterpret_cast<ushort4*>(out)[j] = o;
  }
}

// ------- W [H][K][N] f32 -> Wt [H][N][K] bf16, 64x64 LDS-tiled ---------
__global__ void transpose_cvt(const float* __restrict__ W, u16* __restrict__ Wt,
                              int K, int N) {
  __shared__ u16 t[64][66];
  const int a = blockIdx.z;
  const int n0 = blockIdx.x * 64, k0 = blockIdx.y * 64;
  const float* Wh = W + (size_t)a * K * N;
  u16* Wth = Wt + (size_t)a * N * K;
  const int tid = threadIdx.x;
#pragma unroll
  for (int j = 0; j < 16; ++j) {
    int idx = j * 256 + tid;
    int r = idx >> 6, c = idx & 63;
    t[r][c] = f2bf(Wh[(size_t)(k0 + r) * N + n0 + c]);
  }
  __syncthreads();
#pragma unroll
  for (int j = 0; j < 16; ++j) {
    int idx = j * 256 + tid;
    int r = idx >> 6, c = idx & 63;
    Wth[(size_t)(n0 + r) * K + k0 + c] = t[c][r];
  }
}

// ---- batched-head GEMM, 128x128 tile, BK=64, m97 structure + swizzle ----
// 32 KiB LDS, 256 thr (4 waves, 2x2), ~2.7 blocks/CU: cross-block TLP hides
// prologue/epilogue/barrier stalls (m114). Both-sides XOR swizzle (slot
// j^(row&7) on global src, same XOR on ds_read) -> 0 bank conflicts
// (verified round 3). XCD-bijective blockIdx swizzle for L2 locality.
// MODE 1: outBf[h][M][N] = bf16(tanh(A@B + bias))
// MODE 2: atomicAdd muAcc[row][h] += sum_col tanh(A@B+bias)*W3[h][col]
template <int MODE>
__global__ __launch_bounds__(256, 2) void gemm_heads(
    const u16* __restrict__ A, long aHeadStride,
    const u16* __restrict__ Bt,
    const float* __restrict__ bias,
    int M, int N, int K, int gridN,
    u16* __restrict__ outBf,
    const float* __restrict__ W3,
    float* __restrict__ muAcc) {
  __shared__ __align__(16) u16 As[128 * 64];
  __shared__ __align__(16) u16 Bs[128 * 64];

  const int tid = threadIdx.x;
  const int l = tid & 63;
  const int w = tid >> 6;
  const int wm = w >> 1, wn = w & 1;     // 2x2 waves, 64x64 each
  const int lh = l & 15, lg = l >> 4;

  // T1: bijective XCD swizzle (gridDim.x % 8 == 0 by construction)
  const int cpx = gridDim.x >> 3;
  const int bid = (blockIdx.x & 7) * cpx + (blockIdx.x >> 3);
  const int bph = (M >> 7) * gridN;      // blocks per head
  const int head = bid / bph;
  const int rem = bid % bph;
  const int m0 = (rem / gridN) << 7;     // n-minor: B panel stays L2-hot
  const int n0 = (rem % gridN) << 7;

  const u16* Ah = A + (size_t)head * (size_t)aHeadStride;
  const u16* Bh = Bt + (size_t)head * (size_t)N * (size_t)K;

  f32x4 acc[4][4] = {};

  for (int kt = 0; kt < K; kt += 64) {
    // stage A/B tiles [128][64]; linear LDS dest, pre-swizzled global src
#pragma unroll
    for (int i = 0; i < 4; ++i) {
      const int c = i * 256 + tid;
      const int row = c >> 3, j = c & 7;
      const int js = j ^ (row & 7);
      load_lds16(Ah + (size_t)(m0 + row) * K + kt + js * 8, &As[c * 8]);
    }
#pragma unroll
    for (int i = 0; i < 4; ++i) {
      const int c = i * 256 + tid;
      const int row = c >> 3, j = c & 7;
      const int js = j ^ (row & 7);
      load_lds16(Bh + (size_t)(n0 + row) * K + kt + js * 8, &Bs[c * 8]);
    }
    __syncthreads();

#pragma unroll
    for (int ks = 0; ks < 2; ++ks) {
      bf16x8 af[4], bfr[4];
#pragma unroll
      for (int mf = 0; mf < 4; ++mf) {
        const int row = wm * 64 + mf * 16 + lh;
        const int j = (ks * 4 + lg) ^ (lh & 7);
        af[mf] = *reinterpret_cast<const bf16x8*>(&As[row * 64 + j * 8]);
      }
#pragma unroll
      for (int nf = 0; nf < 4; ++nf) {
        const int row = wn * 64 + nf * 16 + lh;
        const int j = (ks * 4 + lg) ^ (lh & 7);
        bfr[nf] = *reinterpret_cast<const bf16x8*>(&Bs[row * 64 + j * 8]);
      }
#pragma unroll
      for (int mf = 0; mf < 4; ++mf)
#pragma unroll
        for (int nf = 0; nf < 4; ++nf)
          acc[mf][nf] = __builtin_amdgcn_mfma_f32_16x16x32_bf16(
              af[mf], bfr[nf], acc[mf][nf], 0, 0, 0);
    }
    __syncthreads();
  }

  if (MODE == 1) {
    u16* Oh = outBf + (size_t)head * (size_t)M * (size_t)N;
#pragma unroll
    for (int mf = 0; mf < 4; ++mf) {
#pragma unroll
      for (int r = 0; r < 4; ++r) {
        const int row = m0 + wm * 64 + mf * 16 + lg * 4 + r;
#pragma unroll
        for (int nf = 0; nf < 4; ++nf) {
          const int col = n0 + wn * 64 + nf * 16 + lh;
          float v = acc[mf][nf][r] + bias[head * N + col];
          Oh[(size_t)row * N + col] = f2bf(fast_tanh(v));
        }
      }
    }
  } else {
#pragma unroll
    for (int mf = 0; mf < 4; ++mf) {
#pragma unroll
      for (int r = 0; r < 4; ++r) {
        const int row = m0 + wm * 64 + mf * 16 + lg * 4 + r;
        float p = 0.f;
#pragma unroll
        for (int nf = 0; nf < 4; ++nf) {
          const int col = n0 + wn * 64 + nf * 16 + lh;
          float v = acc[mf][nf][r] + bias[head * N + col];
          p += fast_tanh(v) * W3[head * N + col];
        }
        p += __shfl_xor(p, 1);
        p += __shfl_xor(p, 2);
        p += __shfl_xor(p, 4);
        p += __shfl_xor(p, 8);
        if (lh == 0) atomicAdd(&muAcc[(size_t)row * 32 + head], p);
      }
    }
  }
}

// ------------- finalize: mu = acc + b3; logp reduction -------------
__global__ void finalize_kernel(const float* __restrict__ muAcc,
                                const float* __restrict__ b3,
                                const float* __restrict__ lstd,
                                const float* __restrict__ act,
                                float* __restrict__ out, int M) {
  int b = blockIdx.x * 256 + threadIdx.x;
  if (b >= M) return;
  float lp = 0.f;
#pragma unroll
  for (int a = 0; a < 32; ++a) {
    float mu = muAcc[(size_t)b * 32 + a] + b3[a];
    out[(size_t)b * 32 + a] = mu;
    float ls = lstd[a];
    float z = (act[(size_t)b * 32 + a] - mu) * __expf(-ls);
    lp += -0.5f * (z * z + LOG2PI_F) - ls;
  }
  out[(size_t)M * 32 + b] = lp;
}

extern "C" void kernel_launch(void* const* d_in, const int* in_sizes, int n_in,
                              void* d_out, int out_size, void* d_ws, size_t ws_size,
                              hipStream_t stream) {
  const float* obs = (const float*)d_in[0];
  const float* act = (const float*)d_in[1];
  const float* W1 = (const float*)d_in[2];
  const float* b1 = (const float*)d_in[3];
  const float* W2 = (const float*)d_in[4];
  const float* b2 = (const float*)d_in[5];
  const float* W3 = (const float*)d_in[6];
  const float* b3 = (const float*)d_in[7];
  const float* lstd = (const float*)d_in[8];

  constexpr int B = 4096, OBS = 512, A = 32, H1 = 1024, H2 = 1024;

  u16* obs_bf = (u16*)d_ws;                              // [B][OBS]
  u16* W1t = obs_bf + (size_t)B * OBS;                   // [A][H1][OBS]
  u16* W2t = W1t + (size_t)A * H1 * OBS;                 // [A][H2][H1]
  u16* x1 = W2t + (size_t)A * H2 * H1;                   // [A][B][H1]
  float* muAcc = (float*)(x1 + (size_t)A * B * H1);      // [B][A]
  float* out = (float*)d_out;

  hipMemsetAsync(muAcc, 0, (size_t)B * A * sizeof(float), stream);

  cvt_f32_bf16<<<1024, 256, 0, stream>>>(obs, obs_bf, B * OBS / 4);
  transpose_cvt<<<dim3(H1 / 64, OBS / 64, A), 256, 0, stream>>>(W1, W1t, OBS, H1);
  transpose_cvt<<<dim3(H2 / 64, H1 / 64, A), 256, 0, stream>>>(W2, W2t, H1, H2);

  // 8192 blocks each (divisible by 8 for the XCD swizzle)
  gemm_heads<1><<<(B / 128) * (H1 / 128) * A, 256, 0, stream>>>(
      obs_bf, 0L, W1t, b1, B, H1, OBS, H1 / 128, x1, nullptr, nullptr);

  gemm_heads<2><<<(B / 128) * (H2 / 128) * A, 256, 0, stream>>>(
      x1, (long)B * H1, W2t, b2, B, H2, H1, H2 / 128, nullptr, W3, muAcc);

  finalize_kernel<<<B / 256, 256, 0, stream>>>(muAcc, b3, lstd, act, out, B);
}